// Round 10
// baseline (217.633 us; speedup 1.0000x reference)
//
#include <hip/hip_runtime.h>
#include <hip/hip_bf16.h>

typedef __attribute__((ext_vector_type(8))) short bf16x8;
typedef __attribute__((ext_vector_type(16))) float f32x16;
typedef __attribute__((ext_vector_type(2))) unsigned u32x2;

// packed f32x2 -> bf16x2 (RNE)
__device__ __forceinline__ unsigned pk2(float a, float b) {
    union { __hip_bfloat162 h2; unsigned u; } c;
    c.h2 = __float22bfloat162_rn(make_float2(a, b));
    return c.u;
}

// async global->LDS DMA, 16 B/lane; LDS dest = wave-uniform base + lane*16
__device__ __forceinline__ void gld16(const void* g, void* l) {
    __builtin_amdgcn_global_load_lds(
        (const __attribute__((address_space(1))) unsigned*)g,
        (__attribute__((address_space(3))) unsigned*)l, 16, 0, 0);
}

// exact transcription of the reference _hilbert_index_to_xy; returns p = x*d + y
__device__ inline int hilbert_p(int index, int d) {
    int x = 0, y = 0;
    for (int s = 1; s < d; s <<= 1) {
        int rx = (index >> 1) & 1;
        int ry = (index ^ rx) & 1;
        if (ry == 0) {
            if (rx == 1) {
                int nx = s - 1 - y;
                int ny = s - 1 - x;
                x = nx; y = ny;
            }
            int t = x; x = y; y = t;
        }
        x += s * rx;
        y += s * ry;
        index >>= 2;
    }
    return x * d + y;
}

// ---- tile geometry decode (tile index 0..1119) ----
struct TileGeo { int g, h, segrow, dgrid, kt; };
__device__ __forceinline__ TileGeo tile_decode(int b) {
    TileGeo t;
    int g, rb;
    if (b < 640)      { g = 0; rb = b; }
    else if (b < 960) { g = 1; rb = b - 640; }
    else              { g = 2; rb = b - 960; }
    const int nseg = 4 >> g;
    const int hl   = rb / (nseg * 32);
    const int r2   = rb - hl * (nseg * 32);
    t.g      = g;
    t.h      = g * 5 + hl;
    t.kt     = r2 & 31;
    t.segrow = (r2 >> 5) * (2048 << g);
    t.dgrid  = (g == 2) ? 128 : 64;
    return t;
}

// ---- gather (~8 us total, pinned by R8's fusion experiment — not the
// bottleneck). Chunk-linear layouts (R6+, unchanged):
//   kchunk(j,c8)  = ((j>>5)*4 + (c8>>1))*64 + (c8&1)*32 + (j&31)
//   vchunk(dd,k8) = ((k8>>1)*2 + (dd>>5))*64 + (k8&1)*32 + (dd&31)
__device__ __forceinline__ void k_item(int i, const float* __restrict__ K,
                                       short* __restrict__ Kp) {
    const int tile = i >> 9, idx = i & 511;
    const int j = idx >> 3, c8 = idx & 7;
    const TileGeo t = tile_decode(tile);
    const int ii = t.kt * 64 + j;
    const int p  = (t.g == 0) ? ii : hilbert_p(ii << t.g, t.dgrid);
    const float* kp = K + ((size_t)((t.segrow + p) * 16 + t.h)) * 64 + c8 * 8;
    float4 k0 = ((const float4*)kp)[0];
    float4 k1 = ((const float4*)kp)[1];
    union { unsigned u4[4]; bf16x8 v; } ck;
    ck.u4[0] = pk2(k0.x, k0.y); ck.u4[1] = pk2(k0.z, k0.w);
    ck.u4[2] = pk2(k1.x, k1.y); ck.u4[3] = pk2(k1.z, k1.w);
    const int kchunk = ((j >> 5) * 4 + (c8 >> 1)) * 64 + (c8 & 1) * 32 + (j & 31);
    *(bf16x8*)&Kp[(size_t)tile * 4096 + kchunk * 8] = ck.v;
}

__device__ __forceinline__ void v_item(int i, const float* __restrict__ V,
                                       short* __restrict__ Vp) {
    const int tile = i >> 9, idx = i & 511;
    const int k8 = idx >> 6, dd = idx & 63;
    const TileGeo t = tile_decode(tile);
    float rv[8];
#pragma unroll
    for (int u = 0; u < 8; ++u) {
        const int ii = t.kt * 64 + k8 * 8 + u;
        const int p  = (t.g == 0) ? ii : hilbert_p(ii << t.g, t.dgrid);
        rv[u] = V[((size_t)((t.segrow + p) * 16 + t.h)) * 64 + dd];
    }
    union { unsigned u4[4]; bf16x8 v; } o;
    o.u4[0] = pk2(rv[0], rv[1]); o.u4[1] = pk2(rv[2], rv[3]);
    o.u4[2] = pk2(rv[4], rv[5]); o.u4[3] = pk2(rv[6], rv[7]);
    const int vchunk = ((k8 >> 1) * 2 + (dd >> 5)) * 64 + (k8 & 1) * 32 + (dd & 31);
    *(bf16x8*)&Vp[(size_t)tile * 4096 + vchunk * 8] = o.v;
}

__global__ __launch_bounds__(256, 4) void gather_kv(
    const float* __restrict__ K, const float* __restrict__ V,
    short* __restrict__ Kp, short* __restrict__ Vp)
{
    const int gt   = blockIdx.x * 256 + threadIdx.x;
    const int step = gridDim.x * 256;
    for (int i = gt; i < 1120 * 512; i += step) k_item(i, K, Kp);
    for (int i = gt; i < 1120 * 512; i += step) v_item(i, V, Vp);
}

// R10: 64 QUERIES PER WAVE (2 q-sets), 2-wave blocks, same 960-block grid.
// Pipe arithmetic from R0-R9 counters: at 32 q/wave each b128 LDS read fed
// exactly ONE MFMA (12 cyc LDS vs 8 cyc MFMA per CU) -> the shared LDS unit
// co-saturated with the matrix pipe and pinned MfmaUtil at ~26%. Q and P are
// register-resident, so doubling queries/wave makes every kf/vf read feed
// TWO MFMAs: LDS reads per CU halve, kernel flips to MFMA-bound.
//  - within-wave ILP doubles (2 independent MFMA/exp2 chains interleaved),
//    compensating the TLP drop (1.9 waves/SIMD).
//  - single-barrier pipeline (R9), dbuf LDS, counted vmcnt, chunk-linear
//    layouts, in-register P via cvt_pk + permlane32_swap: all unchanged.
//  - VGPR ~200-230 under the 256 cap of __launch_bounds__(128,2); a spill
//    would show as a WRITE_SIZE jump (R2 signature).
__global__ __launch_bounds__(128, 2) void attn_kernel(
    const float* __restrict__ Q, float* __restrict__ O,
    const short* __restrict__ Kp, const short* __restrict__ Vp)
{
    __shared__ __align__(16) short ldsK[2][4096];  // 2 x 8 KB, chunk-linear
    __shared__ __align__(16) short ldsV[2][4096];  // 2 x 8 KB, chunk-linear

    const int bx = blockIdx.x;
    const int g  = bx / 320;
    const int r  = bx - g * 320;
    const int hl = r >> 6;
    const int qb = r & 63;
    const int h  = g * 5 + hl;
    const int qglob = qb * 128;
    const int seg   = qb >> (4 + g);
    const int tile0 = ((g == 0) ? 0 : (g == 1) ? 640 : 960) + (hl * (4 >> g) + seg) * 32;

    const int tid  = threadIdx.x;
    const int wave = tid >> 6;
    const int lane = tid & 63;
    const int l31  = lane & 31;
    const int hi   = lane >> 5;

    // head 15 belongs to no group: zero it here (d_out is poisoned each run).
    if (g == 0 && hl == 0) {
        const float4 z = make_float4(0.f, 0.f, 0.f, 0.f);
        for (int i = tid; i < 2048; i += 128) {
            int row = qglob + (i >> 4);
            ((float4*)O)[(size_t)(row * 16 + 15) * 16 + (i & 15)] = z;
        }
    }

    // ---- Q fragments, two query-sets per wave:
    // set A: q = qglob + wave*64 + l31 ; set B: q = +32
    const float cs = 0.125f * 1.44269504088896f;   // scale * log2(e)
    bf16x8 qfA[4], qfB[4];
#pragma unroll
    for (int qs = 0; qs < 2; ++qs) {
        const int qrow = qglob + wave * 64 + qs * 32 + l31;
        const float* qp = Q + ((size_t)(qrow * 16 + h)) * 64;
#pragma unroll
        for (int ks = 0; ks < 4; ++ks) {
            const float4* p4 = (const float4*)(qp + ks * 16 + hi * 8);
            float4 a = p4[0], b = p4[1];
            union { unsigned u[4]; bf16x8 v; } f;
            f.u[0] = pk2(a.x * cs, a.y * cs); f.u[1] = pk2(a.z * cs, a.w * cs);
            f.u[2] = pk2(b.x * cs, b.y * cs); f.u[3] = pk2(b.z * cs, b.w * cs);
            if (qs == 0) qfA[ks] = f.v; else qfB[ks] = f.v;
        }
    }

    f32x16 z16;
#pragma unroll
    for (int rr = 0; rr < 16; ++rr) z16[rr] = 0.f;

    f32x16 oaccA0 = z16, oaccA1 = z16, oaccB0 = z16, oaccB1 = z16;
    float lpA = 0.f, lpB = 0.f;

    const int lbase = lane * 8;   // fragment base in shorts (lane*16 B)

    // ---- staging: 2 waves split the 8 KB K + 8 KB V tile; 4 gld16 each for
    // K (wave half = 4 KB) + 4 for V. 8 DMAs outstanding per wave.
    // prologue: tile 0 -> buffer 0
    {
        const size_t tb = (size_t)tile0 << 13;
        const char* kgp = (const char*)Kp + tb + (wave << 12) + (lane << 4);
        const char* vgp = (const char*)Vp + tb + (wave << 12) + (lane << 4);
        char* klp = (char*)&ldsK[0][0] + (wave << 12);
        char* vlp = (char*)&ldsV[0][0] + (wave << 12);
        gld16(kgp,        klp);        gld16(kgp + 1024, klp + 1024);
        gld16(kgp + 2048, klp + 2048); gld16(kgp + 3072, klp + 3072);
        gld16(vgp,        vlp);        gld16(vgp + 1024, vlp + 1024);
        gld16(vgp + 2048, vlp + 2048); gld16(vgp + 3072, vlp + 3072);
    }

    for (int kt = 0; kt < 32; ++kt) {
        const int cur = kt & 1;

        // own DMAs (issued a full compute phase ago) drained, then the single
        // barrier: proves tile kt staged AND all reads of buf[cur^1] done.
        asm volatile("s_waitcnt vmcnt(0)" ::: "memory");
        asm volatile("s_barrier" ::: "memory");

        if (kt < 31) {
            const size_t tb = (size_t)(tile0 + kt + 1) << 13;
            const char* kgp = (const char*)Kp + tb + (wave << 12) + (lane << 4);
            const char* vgp = (const char*)Vp + tb + (wave << 12) + (lane << 4);
            char* klp = (char*)&ldsK[cur ^ 1][0] + (wave << 12);
            char* vlp = (char*)&ldsV[cur ^ 1][0] + (wave << 12);
            gld16(kgp,        klp);        gld16(kgp + 1024, klp + 1024);
            gld16(kgp + 2048, klp + 2048); gld16(kgp + 3072, klp + 3072);
            gld16(vgp,        vlp);        gld16(vgp + 1024, vlp + 1024);
            gld16(vgp + 2048, vlp + 2048); gld16(vgp + 3072, vlp + 3072);
        }

        const short* lK = &ldsK[cur][lbase];
        const short* lV = &ldsV[cur][lbase];

        // ---- S-phase: per 32-key block, TWO interleaved MFMA chains (one
        // per q-set) share the same kf reads. m(reg,hi)=(reg&3)+8*(reg>>2)+4*hi
        float laccA = 0.f, laccB = 0.f;
        unsigned dwA[16], dwB[16];
        __builtin_amdgcn_s_setprio(1);
#pragma unroll
        for (int kb = 0; kb < 2; ++kb) {
            bf16x8 kf0 = *(const bf16x8*)&lK[(kb * 4 + 0) * 512];
            bf16x8 kf1 = *(const bf16x8*)&lK[(kb * 4 + 1) * 512];
            bf16x8 kf2 = *(const bf16x8*)&lK[(kb * 4 + 2) * 512];
            bf16x8 kf3 = *(const bf16x8*)&lK[(kb * 4 + 3) * 512];
            f32x16 sa0, sa1;
            sa0 = __builtin_amdgcn_mfma_f32_32x32x16_bf16(kf0, qfA[0], z16, 0, 0, 0);
            sa1 = __builtin_amdgcn_mfma_f32_32x32x16_bf16(kf0, qfB[0], z16, 0, 0, 0);
            sa0 = __builtin_amdgcn_mfma_f32_32x32x16_bf16(kf1, qfA[1], sa0, 0, 0, 0);
            sa1 = __builtin_amdgcn_mfma_f32_32x32x16_bf16(kf1, qfB[1], sa1, 0, 0, 0);
            sa0 = __builtin_amdgcn_mfma_f32_32x32x16_bf16(kf2, qfA[2], sa0, 0, 0, 0);
            sa1 = __builtin_amdgcn_mfma_f32_32x32x16_bf16(kf2, qfB[2], sa1, 0, 0, 0);
            sa0 = __builtin_amdgcn_mfma_f32_32x32x16_bf16(kf3, qfA[3], sa0, 0, 0, 0);
            sa1 = __builtin_amdgcn_mfma_f32_32x32x16_bf16(kf3, qfB[3], sa1, 0, 0, 0);

            float peA[16], peB[16];
#pragma unroll
            for (int rr = 0; rr < 16; ++rr) peA[rr] = __builtin_amdgcn_exp2f(sa0[rr]);
#pragma unroll
            for (int rr = 0; rr < 16; ++rr) peB[rr] = __builtin_amdgcn_exp2f(sa1[rr]);
            laccA += (((peA[0] + peA[1]) + (peA[2] + peA[3])) + ((peA[4] + peA[5]) + (peA[6] + peA[7])))
                   + (((peA[8] + peA[9]) + (peA[10] + peA[11])) + ((peA[12] + peA[13]) + (peA[14] + peA[15])));
            laccB += (((peB[0] + peB[1]) + (peB[2] + peB[3])) + ((peB[4] + peB[5]) + (peB[6] + peB[7])))
                   + (((peB[8] + peB[9]) + (peB[10] + peB[11])) + ((peB[12] + peB[13]) + (peB[14] + peB[15])));
#pragma unroll
            for (int kslo = 0; kslo < 2; ++kslo)
#pragma unroll
                for (int j = 0; j < 2; ++j)
#pragma unroll
                    for (int hT = 0; hT < 2; ++hT) {
                        const int r0 = 2 * j + 8 * kslo + 4 * hT;
                        const int di = (kb * 2 + kslo) * 4 + j * 2 + hT;
                        dwA[di] = pk2(peA[r0], peA[r0 + 1]);
                        dwB[di] = pk2(peB[r0], peB[r0 + 1]);
                    }
        }
        __builtin_amdgcn_s_setprio(0);
        lpA += laccA; lpB += laccB;

        // ---- assemble PV A-frags per q-set via permlane32_swap
        bf16x8 paA[4], paB[4];
#pragma unroll
        for (int ks = 0; ks < 4; ++ks) {
            u32x2 a0 = __builtin_amdgcn_permlane32_swap(dwA[ks * 4 + 0], dwA[ks * 4 + 1], false, false);
            u32x2 a1 = __builtin_amdgcn_permlane32_swap(dwA[ks * 4 + 2], dwA[ks * 4 + 3], false, false);
            u32x2 b0 = __builtin_amdgcn_permlane32_swap(dwB[ks * 4 + 0], dwB[ks * 4 + 1], false, false);
            u32x2 b1 = __builtin_amdgcn_permlane32_swap(dwB[ks * 4 + 2], dwB[ks * 4 + 3], false, false);
            union { unsigned u[4]; bf16x8 v; } pA, pB;
            pA.u[0] = a0[0]; pA.u[1] = a1[0]; pA.u[2] = a0[1]; pA.u[3] = a1[1];
            pB.u[0] = b0[0]; pB.u[1] = b1[0]; pB.u[2] = b0[1]; pB.u[3] = b1[1];
            paA[ks] = pA.v;  paB[ks] = pB.v;
        }

        __builtin_amdgcn_sched_barrier(0);   // keep vf out of the S live range

        // ---- V B-fragments: shared by both q-sets (2 MFMAs per read)
        bf16x8 vf[4][2];
#pragma unroll
        for (int ks = 0; ks < 4; ++ks)
#pragma unroll
            for (int db = 0; db < 2; ++db)
                vf[ks][db] = *(const bf16x8*)&lV[(ks * 2 + db) * 512];

        __builtin_amdgcn_s_setprio(1);
#pragma unroll
        for (int ks = 0; ks < 4; ++ks) {
            oaccA0 = __builtin_amdgcn_mfma_f32_32x32x16_bf16(paA[ks], vf[ks][0], oaccA0, 0, 0, 0);
            oaccB0 = __builtin_amdgcn_mfma_f32_32x32x16_bf16(paB[ks], vf[ks][0], oaccB0, 0, 0, 0);
            oaccA1 = __builtin_amdgcn_mfma_f32_32x32x16_bf16(paA[ks], vf[ks][1], oaccA1, 0, 0, 0);
            oaccB1 = __builtin_amdgcn_mfma_f32_32x32x16_bf16(paB[ks], vf[ks][1], oaccB1, 0, 0, 0);
        }
        __builtin_amdgcn_s_setprio(0);
        // no bottom barrier: next iteration's top barrier orders the
        // buf[cur] overwrite against this iteration's reads.
    }

    // ---- l reduction (per q-set): halves live at (l31, hi=0/1)
    float ltA = lpA + __shfl_xor(lpA, 32, 64);
    float ltB = lpB + __shfl_xor(lpB, 32, 64);
    float invA = 1.0f / ltA;
    float invB = 1.0f / ltB;

    // ---- epilogue: row = q = (rr&3)+8*(rr>>2)+4*hi, col = l31 / 32+l31
#pragma unroll
    for (int rr = 0; rr < 16; ++rr) {
        const int m = (rr & 3) + ((rr >> 2) << 3) + (hi << 2);
        float iA = __shfl(invA, m, 64);   // inv for q=m lives at lane m
        float iB = __shfl(invB, m, 64);
        const int qrowA = qglob + wave * 64 + m;
        const int qrowB = qrowA + 32;
        float* opA = O + ((size_t)(qrowA * 16 + h)) * 64 + l31;
        float* opB = O + ((size_t)(qrowB * 16 + h)) * 64 + l31;
        opA[0]  = oaccA0[rr] * iA;
        opA[32] = oaccA1[rr] * iA;
        opB[0]  = oaccB0[rr] * iB;
        opB[32] = oaccB1[rr] * iB;
    }
}

extern "C" void kernel_launch(void* const* d_in, const int* in_sizes, int n_in,
                              void* d_out, int out_size, void* d_ws, size_t ws_size,
                              hipStream_t stream) {
    const float* q = (const float*)d_in[0];
    const float* k = (const float*)d_in[1];
    const float* v = (const float*)d_in[2];
    float* out = (float*)d_out;
    short* Kp = (short*)d_ws;                       // 1120 tiles * 8 KB = 9.18 MB
    short* Vp = Kp + (size_t)1120 * 4096;           // + 9.18 MB  (ws total ~18.4 MB)

    gather_kv<<<960, 256, 0, stream>>>(k, v, Kp, Vp);
    attn_kernel<<<960, 128, 0, stream>>>(q, out, Kp, Vp);
}

// Round 11
// 215.455 us; speedup vs baseline: 1.0101x; 1.0101x over previous
//
#include <hip/hip_runtime.h>
#include <hip/hip_bf16.h>

typedef __attribute__((ext_vector_type(8))) short bf16x8;
typedef __attribute__((ext_vector_type(16))) float f32x16;
typedef __attribute__((ext_vector_type(2))) unsigned u32x2;

// packed f32x2 -> bf16x2 (RNE)
__device__ __forceinline__ unsigned pk2(float a, float b) {
    union { __hip_bfloat162 h2; unsigned u; } c;
    c.h2 = __float22bfloat162_rn(make_float2(a, b));
    return c.u;
}

// async global->LDS DMA, 16 B/lane; LDS dest = wave-uniform base + lane*16
__device__ __forceinline__ void gld16(const void* g, void* l) {
    __builtin_amdgcn_global_load_lds(
        (const __attribute__((address_space(1))) unsigned*)g,
        (__attribute__((address_space(3))) unsigned*)l, 16, 0, 0);
}

// exact transcription of the reference _hilbert_index_to_xy; returns p = x*d + y
__device__ inline int hilbert_p(int index, int d) {
    int x = 0, y = 0;
    for (int s = 1; s < d; s <<= 1) {
        int rx = (index >> 1) & 1;
        int ry = (index ^ rx) & 1;
        if (ry == 0) {
            if (rx == 1) {
                int nx = s - 1 - y;
                int ny = s - 1 - x;
                x = nx; y = ny;
            }
            int t = x; x = y; y = t;
        }
        x += s * rx;
        y += s * ry;
        index >>= 2;
    }
    return x * d + y;
}

// ---- tile geometry decode (tile index 0..1119) ----
struct TileGeo { int g, h, segrow, dgrid, kt; };
__device__ __forceinline__ TileGeo tile_decode(int b) {
    TileGeo t;
    int g, rb;
    if (b < 640)      { g = 0; rb = b; }
    else if (b < 960) { g = 1; rb = b - 640; }
    else              { g = 2; rb = b - 960; }
    const int nseg = 4 >> g;
    const int hl   = rb / (nseg * 32);
    const int r2   = rb - hl * (nseg * 32);
    t.g      = g;
    t.h      = g * 5 + hl;
    t.kt     = r2 & 31;
    t.segrow = (r2 >> 5) * (2048 << g);
    t.dgrid  = (g == 2) ? 128 : 64;
    return t;
}

// ---- gather (~8 us total, pinned by R8's fusion experiment — not the
// bottleneck). Chunk-linear layouts (R6+, unchanged):
//   kchunk(j,c8)  = ((j>>5)*4 + (c8>>1))*64 + (c8&1)*32 + (j&31)
//   vchunk(dd,k8) = ((k8>>1)*2 + (dd>>5))*64 + (k8&1)*32 + (dd&31)
__device__ __forceinline__ void k_item(int i, const float* __restrict__ K,
                                       short* __restrict__ Kp) {
    const int tile = i >> 9, idx = i & 511;
    const int j = idx >> 3, c8 = idx & 7;
    const TileGeo t = tile_decode(tile);
    const int ii = t.kt * 64 + j;
    const int p  = (t.g == 0) ? ii : hilbert_p(ii << t.g, t.dgrid);
    const float* kp = K + ((size_t)((t.segrow + p) * 16 + t.h)) * 64 + c8 * 8;
    float4 k0 = ((const float4*)kp)[0];
    float4 k1 = ((const float4*)kp)[1];
    union { unsigned u4[4]; bf16x8 v; } ck;
    ck.u4[0] = pk2(k0.x, k0.y); ck.u4[1] = pk2(k0.z, k0.w);
    ck.u4[2] = pk2(k1.x, k1.y); ck.u4[3] = pk2(k1.z, k1.w);
    const int kchunk = ((j >> 5) * 4 + (c8 >> 1)) * 64 + (c8 & 1) * 32 + (j & 31);
    *(bf16x8*)&Kp[(size_t)tile * 4096 + kchunk * 8] = ck.v;
}

__device__ __forceinline__ void v_item(int i, const float* __restrict__ V,
                                       short* __restrict__ Vp) {
    const int tile = i >> 9, idx = i & 511;
    const int k8 = idx >> 6, dd = idx & 63;
    const TileGeo t = tile_decode(tile);
    float rv[8];
#pragma unroll
    for (int u = 0; u < 8; ++u) {
        const int ii = t.kt * 64 + k8 * 8 + u;
        const int p  = (t.g == 0) ? ii : hilbert_p(ii << t.g, t.dgrid);
        rv[u] = V[((size_t)((t.segrow + p) * 16 + t.h)) * 64 + dd];
    }
    union { unsigned u4[4]; bf16x8 v; } o;
    o.u4[0] = pk2(rv[0], rv[1]); o.u4[1] = pk2(rv[2], rv[3]);
    o.u4[2] = pk2(rv[4], rv[5]); o.u4[3] = pk2(rv[6], rv[7]);
    const int vchunk = ((k8 >> 1) * 2 + (dd >> 5)) * 64 + (k8 & 1) * 32 + (dd & 31);
    *(bf16x8*)&Vp[(size_t)tile * 4096 + vchunk * 8] = o.v;
}

__global__ __launch_bounds__(256, 4) void gather_kv(
    const float* __restrict__ K, const float* __restrict__ V,
    short* __restrict__ Kp, short* __restrict__ Vp)
{
    const int gt   = blockIdx.x * 256 + threadIdx.x;
    const int step = gridDim.x * 256;
    for (int i = gt; i < 1120 * 512; i += step) k_item(i, K, Kp);
    for (int i = gt; i < 1120 * 512; i += step) v_item(i, V, Vp);
}

// R11 = R9 + l-VIA-MFMA: the softmax denominator l[q] = sum_k P[q][k] is a
// matrix-vector product -> computed by 4 extra MFMAs/wave-tile against an
// all-ones B operand, accumulated in oL (f32x16). Deletes per-tile 32 VALU
// adds + 2 shfl_xor + 16 epilogue shuffles: the MFMA D-layout lands l[m]
// IN-LANE exactly where the epilogue divides (row m(rr,hi), any col).
// Also makes l consistent with the PV numerator (both use bf16-rounded P).
// R0-R10 evidence: wall = multi-pipe dependency plateau (MFMA 26% + VALU 43%
// + LDS ~25%, flat across 7 structures, flat in TLP both directions) ->
// shift work from the most-loaded pipe (VALU) to the least (MFMA).
// Everything else unchanged from R9: 32x32x16 MFMA, in-register P via
// cvt_pk + permlane32_swap, single-barrier pipeline, dbuf LDS, chunk-linear
// layouts, 0 bank conflicts.
__global__ __launch_bounds__(256, 4) void attn_kernel(
    const float* __restrict__ Q, float* __restrict__ O,
    const short* __restrict__ Kp, const short* __restrict__ Vp)
{
    __shared__ __align__(16) short ldsK[2][4096];  // 2 x 8 KB, chunk-linear
    __shared__ __align__(16) short ldsV[2][4096];  // 2 x 8 KB, chunk-linear

    const int bx = blockIdx.x;
    const int g  = bx / 320;
    const int r  = bx - g * 320;
    const int hl = r >> 6;
    const int qb = r & 63;
    const int h  = g * 5 + hl;
    const int qglob = qb * 128;
    const int seg   = qb >> (4 + g);
    const int tile0 = ((g == 0) ? 0 : (g == 1) ? 640 : 960) + (hl * (4 >> g) + seg) * 32;

    const int tid  = threadIdx.x;
    const int wave = tid >> 6;
    const int lane = tid & 63;
    const int l31  = lane & 31;
    const int hi   = lane >> 5;

    // head 15 belongs to no group: zero it here (d_out is poisoned each run).
    if (g == 0 && hl == 0) {
        const float4 z = make_float4(0.f, 0.f, 0.f, 0.f);
        for (int i = tid; i < 2048; i += 256) {
            int row = qglob + (i >> 4);
            ((float4*)O)[(size_t)(row * 16 + 15) * 16 + (i & 15)] = z;
        }
    }

    // ---- Q fragments (B-operand of S^T = K.Q^T, 32x32x16)
    const float cs = 0.125f * 1.44269504088896f;   // scale * log2(e)
    bf16x8 qf[4];
    {
        const int qrow = qglob + wave * 32 + l31;
        const float* qp = Q + ((size_t)(qrow * 16 + h)) * 64;
#pragma unroll
        for (int ks = 0; ks < 4; ++ks) {
            const float4* p4 = (const float4*)(qp + ks * 16 + hi * 8);
            float4 a = p4[0], b = p4[1];
            union { unsigned u[4]; bf16x8 v; } f;
            f.u[0] = pk2(a.x * cs, a.y * cs); f.u[1] = pk2(a.z * cs, a.w * cs);
            f.u[2] = pk2(b.x * cs, b.y * cs); f.u[3] = pk2(b.z * cs, b.w * cs);
            qf[ks] = f.v;
        }
    }

    // all-ones bf16 B-fragment for the l row-sum MFMA
    bf16x8 ones;
    {
        union { unsigned u[4]; bf16x8 v; } o;
        o.u[0] = 0x3F803F80u; o.u[1] = 0x3F803F80u;
        o.u[2] = 0x3F803F80u; o.u[3] = 0x3F803F80u;
        ones = o.v;
    }

    f32x16 z16;
#pragma unroll
    for (int rr = 0; rr < 16; ++rr) z16[rr] = 0.f;

    f32x16 oacc[2];
    oacc[0] = z16; oacc[1] = z16;
    f32x16 oL = z16;           // l accumulator: oL[rr] = l[m(rr,hi)]

    const int lbase = lane * 8;   // fragment base in shorts (lane*16 B)

    // ---- prologue: stage tile 0 into buffer 0
    {
        const size_t tb = (size_t)tile0 << 13;   // 8 KB per tile
        const char* kgp = (const char*)Kp + tb + (wave << 11) + (lane << 4);
        const char* vgp = (const char*)Vp + tb + (wave << 11) + (lane << 4);
        char* klp = (char*)&ldsK[0][0] + (wave << 11);
        char* vlp = (char*)&ldsV[0][0] + (wave << 11);
        gld16(kgp,        klp);
        gld16(kgp + 1024, klp + 1024);
        gld16(vgp,        vlp);
        gld16(vgp + 1024, vlp + 1024);
    }

    for (int kt = 0; kt < 32; ++kt) {
        const int cur = kt & 1;

        // ---- own DMAs (issued a full compute phase ago) drained, then ONE
        // barrier: tile kt staged AND all reads of buf[cur^1] complete.
        asm volatile("s_waitcnt vmcnt(0)" ::: "memory");
        asm volatile("s_barrier" ::: "memory");

        if (kt < 31) {
            const size_t tb = (size_t)(tile0 + kt + 1) << 13;
            const char* kgp = (const char*)Kp + tb + (wave << 11) + (lane << 4);
            const char* vgp = (const char*)Vp + tb + (wave << 11) + (lane << 4);
            char* klp = (char*)&ldsK[cur ^ 1][0] + (wave << 11);
            char* vlp = (char*)&ldsV[cur ^ 1][0] + (wave << 11);
            gld16(kgp,        klp);
            gld16(kgp + 1024, klp + 1024);
            gld16(vgp,        vlp);
            gld16(vgp + 1024, vlp + 1024);
        }

        const short* lK = &ldsK[cur][lbase];
        const short* lV = &ldsV[cur][lbase];

        // ---- S-phase: S^T = K.Q^T, exp2, pack. m(reg,hi)=(reg&3)+8*(reg>>2)+4*hi
        unsigned dw[16];   // dw[ks*4 + j*2 + hT]
        __builtin_amdgcn_s_setprio(1);
#pragma unroll
        for (int kb = 0; kb < 2; ++kb) {
            bf16x8 kf0 = *(const bf16x8*)&lK[(kb * 4 + 0) * 512];
            bf16x8 kf1 = *(const bf16x8*)&lK[(kb * 4 + 1) * 512];
            bf16x8 kf2 = *(const bf16x8*)&lK[(kb * 4 + 2) * 512];
            bf16x8 kf3 = *(const bf16x8*)&lK[(kb * 4 + 3) * 512];
            f32x16 sa;
            sa = __builtin_amdgcn_mfma_f32_32x32x16_bf16(kf0, qf[0], z16, 0, 0, 0);
            sa = __builtin_amdgcn_mfma_f32_32x32x16_bf16(kf1, qf[1], sa, 0, 0, 0);
            sa = __builtin_amdgcn_mfma_f32_32x32x16_bf16(kf2, qf[2], sa, 0, 0, 0);
            sa = __builtin_amdgcn_mfma_f32_32x32x16_bf16(kf3, qf[3], sa, 0, 0, 0);
            float pe[16];
#pragma unroll
            for (int rr = 0; rr < 16; ++rr) pe[rr] = __builtin_amdgcn_exp2f(sa[rr]);
            // NO lacc adds: l comes from the ones-MFMA in the PV phase.
#pragma unroll
            for (int kslo = 0; kslo < 2; ++kslo)
#pragma unroll
                for (int j = 0; j < 2; ++j)
#pragma unroll
                    for (int hT = 0; hT < 2; ++hT) {
                        const int r0 = 2 * j + 8 * kslo + 4 * hT;
                        dw[(kb * 2 + kslo) * 4 + j * 2 + hT] = pk2(pe[r0], pe[r0 + 1]);
                    }
        }
        __builtin_amdgcn_s_setprio(0);

        // ---- assemble PV A-frags via permlane32_swap
        bf16x8 pa[4];
#pragma unroll
        for (int ks = 0; ks < 4; ++ks) {
            u32x2 r0 = __builtin_amdgcn_permlane32_swap(dw[ks * 4 + 0], dw[ks * 4 + 1], false, false);
            u32x2 r1 = __builtin_amdgcn_permlane32_swap(dw[ks * 4 + 2], dw[ks * 4 + 3], false, false);
            union { unsigned u[4]; bf16x8 v; } p;
            p.u[0] = r0[0]; p.u[1] = r1[0]; p.u[2] = r0[1]; p.u[3] = r1[1];
            pa[ks] = p.v;
        }

        __builtin_amdgcn_sched_barrier(0);   // keep vf out of the S live range

        bf16x8 vf[4][2];
#pragma unroll
        for (int ks = 0; ks < 4; ++ks)
#pragma unroll
            for (int db = 0; db < 2; ++db)
                vf[ks][db] = *(const bf16x8*)&lV[(ks * 2 + db) * 512];

        // ---- PV + l: O += P.V ; l += P.1  (row-sum on the matrix pipe)
        __builtin_amdgcn_s_setprio(1);
#pragma unroll
        for (int ks = 0; ks < 4; ++ks) {
            oacc[0] = __builtin_amdgcn_mfma_f32_32x32x16_bf16(pa[ks], vf[ks][0], oacc[0], 0, 0, 0);
            oacc[1] = __builtin_amdgcn_mfma_f32_32x32x16_bf16(pa[ks], vf[ks][1], oacc[1], 0, 0, 0);
            oL      = __builtin_amdgcn_mfma_f32_32x32x16_bf16(pa[ks], ones,      oL,      0, 0, 0);
        }
        __builtin_amdgcn_s_setprio(0);
        // no bottom barrier: next iteration's top barrier orders the
        // buf[cur] overwrite against this iteration's reads.
    }

    // ---- epilogue: O / l. oL[rr] = l[m(rr,hi)] (every col holds the row's
    // sum), so the divide is fully in-lane: no shuffles, no reductions.
#pragma unroll
    for (int rr = 0; rr < 16; ++rr) {
        const float inv = 1.0f / oL[rr];
        const int m = (rr & 3) + ((rr >> 2) << 3) + (hi << 2);
        const int qrow = qglob + wave * 32 + m;
        float* op = O + ((size_t)(qrow * 16 + h)) * 64 + l31;
        op[0]  = oacc[0][rr] * inv;
        op[32] = oacc[1][rr] * inv;
    }
}

extern "C" void kernel_launch(void* const* d_in, const int* in_sizes, int n_in,
                              void* d_out, int out_size, void* d_ws, size_t ws_size,
                              hipStream_t stream) {
    const float* q = (const float*)d_in[0];
    const float* k = (const float*)d_in[1];
    const float* v = (const float*)d_in[2];
    float* out = (float*)d_out;
    short* Kp = (short*)d_ws;                       // 1120 tiles * 8 KB = 9.18 MB
    short* Vp = Kp + (size_t)1120 * 4096;           // + 9.18 MB  (ws total ~18.4 MB)

    gather_kv<<<960, 256, 0, stream>>>(k, v, Kp, Vp);
    attn_kernel<<<960, 256, 0, stream>>>(q, out, Kp, Vp);
}